// Round 3
// baseline (277.593 us; speedup 1.0000x reference)
//
#include <hip/hip_runtime.h>
#include <stdint.h>

#define NB 256
#define NL 128
#define ND1 512
#define ND2 512

#define BI 128              // i-tile width per block (n-dim of GEMM)
#define BK 32               // k-tile depth (j-dim)
#define NKT (ND2 / BK)      // 16 k-tiles
#define LDST 40             // LDS row stride (bf16 elems): 80 B rows, 16B-aligned, bank shift 20/row

typedef float float4_t __attribute__((ext_vector_type(4)));
typedef __bf16 bf16x8_t __attribute__((ext_vector_type(8)));
typedef unsigned short ushort4_t __attribute__((ext_vector_type(4)));
typedef unsigned short ushort8_t __attribute__((ext_vector_type(8)));

// fp32 -> bf16 round-to-nearest-even
__device__ __forceinline__ unsigned short f2bf(float f) {
    unsigned int u = __float_as_uint(f);
    u += 0x7FFFu + ((u >> 16) & 1u);
    return (unsigned short)(u >> 16);
}

// Z = T2 (128 x 512, k=j) x W^T (rows j-contiguous); out[b,l] = sum_i Z[l,i]*t1[b,l,i]
__global__ __launch_bounds__(256, 4) void pdot_kernel(
    const float* __restrict__ t1, const float* __restrict__ t2,
    const int* __restrict__ pidx, const float* __restrict__ wgt,
    float* __restrict__ out)
{
    __shared__ unsigned short sA[2][NL * LDST];   // T2 tile bf16 [128 l][32 j + pad], double-buffered
    __shared__ unsigned short sB[2][BI * LDST];   // W  tile bf16 [128 i][32 j + pad]

    const int g  = blockIdx.x;
    const int b  = g & (NB - 1);   // batch in low bits: 4 i-tiles of b co-resident on same CU/XCD -> t1/t2 L2 reuse
    const int it = g >> 8;
    const int i0 = it * BI;

    const int t  = threadIdx.x;
    const int wv = t >> 6;
    const int ln = t & 63;
    const int nh = ln & 15;
    const int qd = ln >> 4;

    const int e = pidx[b];
    const float* aPtr = t2  + (size_t)b * (NL * ND2);
    const float* bPtr = wgt + (size_t)e * (ND1 * ND2) + (size_t)i0 * ND2;
    const float* t1p  = t1  + (size_t)b * (NL * ND1) + i0;

    float4_t acc[2][8];
    #pragma unroll
    for (int i = 0; i < 2; ++i)
        #pragma unroll
        for (int j = 0; j < 8; ++j) {
            float4_t z = {0.f, 0.f, 0.f, 0.f};
            acc[i][j] = z;
        }

    // staging map: thread owns 4 chunks per tile: rows rq+q*32, 16B chunk cq
    const int rq = t >> 3;         // 0..31
    const int cq = (t & 7) * 4;    // fp32 col within tile

    const float* aRow = aPtr + (size_t)rq * ND2 + cq;
    const float* bRow = bPtr + (size_t)rq * ND2 + cq;

    float4_t ra[4], rb[4];         // prefetch registers: 32 VGPRs

    // k-tile fragment read offsets
    const int kf = qd * 8;

    // ---- prologue: load tile 0, store it, load tile 1
    #pragma unroll
    for (int q = 0; q < 4; ++q) {
        ra[q] = *(const float4_t*)(aRow + (size_t)q * 32 * ND2);
        rb[q] = *(const float4_t*)(bRow + (size_t)q * 32 * ND2);
    }
    #pragma unroll
    for (int q = 0; q < 4; ++q) {
        ushort4_t ua, ub;
        ua.x = f2bf(ra[q].x); ua.y = f2bf(ra[q].y); ua.z = f2bf(ra[q].z); ua.w = f2bf(ra[q].w);
        ub.x = f2bf(rb[q].x); ub.y = f2bf(rb[q].y); ub.z = f2bf(rb[q].z); ub.w = f2bf(rb[q].w);
        *(ushort4_t*)(&sA[0][(rq + q * 32) * LDST + cq]) = ua;
        *(ushort4_t*)(&sB[0][(rq + q * 32) * LDST + cq]) = ub;
    }
    #pragma unroll
    for (int q = 0; q < 4; ++q) {
        ra[q] = *(const float4_t*)(aRow + (size_t)q * 32 * ND2 + BK);
        rb[q] = *(const float4_t*)(bRow + (size_t)q * 32 * ND2 + BK);
    }
    __syncthreads();

    // ---- main loop: 1 barrier per k-tile; prefetch regs hide load latency under MFMA
    for (int i = 0; i < NKT; ++i) {
        const int cur = i & 1;

        // MFMA phase: read buf cur, K=32 step
        bf16x8_t af[2];
        bf16x8_t bfr[8];
        #pragma unroll
        for (int ms = 0; ms < 2; ++ms) {
            const int row = wv * 32 + ms * 16 + nh;
            af[ms] = __builtin_bit_cast(bf16x8_t, *(ushort8_t*)(&sA[cur][row * LDST + kf]));
        }
        #pragma unroll
        for (int ns = 0; ns < 8; ++ns) {
            const int nr = ns * 16 + nh;
            bfr[ns] = __builtin_bit_cast(bf16x8_t, *(ushort8_t*)(&sB[cur][nr * LDST + kf]));
        }
        #pragma unroll
        for (int ms = 0; ms < 2; ++ms)
            #pragma unroll
            for (int ns = 0; ns < 8; ++ns)
                acc[ms][ns] = __builtin_amdgcn_mfma_f32_16x16x32_bf16(af[ms], bfr[ns], acc[ms][ns], 0, 0, 0);

        // stage tile i+1 into the other buffer, then refill prefetch regs with tile i+2
        if (i < NKT - 1) {
            const int nxt = cur ^ 1;
            #pragma unroll
            for (int q = 0; q < 4; ++q) {
                ushort4_t ua, ub;
                ua.x = f2bf(ra[q].x); ua.y = f2bf(ra[q].y); ua.z = f2bf(ra[q].z); ua.w = f2bf(ra[q].w);
                ub.x = f2bf(rb[q].x); ub.y = f2bf(rb[q].y); ub.z = f2bf(rb[q].z); ub.w = f2bf(rb[q].w);
                *(ushort4_t*)(&sA[nxt][(rq + q * 32) * LDST + cq]) = ua;
                *(ushort4_t*)(&sB[nxt][(rq + q * 32) * LDST + cq]) = ub;
            }
            if (i < NKT - 2) {
                const size_t ko = (size_t)(i + 2) * BK;
                #pragma unroll
                for (int q = 0; q < 4; ++q) {
                    ra[q] = *(const float4_t*)(aRow + (size_t)q * 32 * ND2 + ko);
                    rb[q] = *(const float4_t*)(bRow + (size_t)q * 32 * ND2 + ko);
                }
            }
        }
        __syncthreads();
    }

    // ---- epilogue: out[b,l] += sum over this i-tile of Z[l,i]*t1[l,i]
    // C/D: col(n=i) = ns*16+nh, row(m=l) = wv*32+ms*16+qd*4+r
    #pragma unroll
    for (int ms = 0; ms < 2; ++ms) {
        #pragma unroll
        for (int r = 0; r < 4; ++r) {
            const int row = wv * 32 + ms * 16 + qd * 4 + r;
            float ps = 0.f;
            #pragma unroll
            for (int ns = 0; ns < 8; ++ns) {
                const float tv = t1p[(size_t)row * ND1 + ns * 16 + nh];
                ps += acc[ms][ns][r] * tv;
            }
            ps += __shfl_xor(ps, 1);
            ps += __shfl_xor(ps, 2);
            ps += __shfl_xor(ps, 4);
            ps += __shfl_xor(ps, 8);
            if (nh == 0) atomicAdd(&out[b * NL + row], ps);
        }
    }
}

extern "C" void kernel_launch(void* const* d_in, const int* in_sizes, int n_in,
                              void* d_out, int out_size, void* d_ws, size_t ws_size,
                              hipStream_t stream)
{
    const float* t1  = (const float*)d_in[0];
    const float* t2  = (const float*)d_in[1];
    const int* pidx  = (const int*)d_in[2];
    const float* wgt = (const float*)d_in[3];
    float* out = (float*)d_out;

    hipMemsetAsync(out, 0, (size_t)out_size * sizeof(float), stream);
    pdot_kernel<<<dim3(NB * (ND1 / BI)), dim3(256), 0, stream>>>(t1, t2, pidx, wgt, out);
}

// Round 4
// 244.012 us; speedup vs baseline: 1.1376x; 1.1376x over previous
//
#include <hip/hip_runtime.h>
#include <stdint.h>

#define NB 256
#define NL 128
#define ND1 512
#define ND2 512

#define BI 64               // i-tile width per block (n-dim of GEMM)
#define BK 32               // k-tile depth (j-dim)
#define NKT (ND2 / BK)      // 16 k-tiles
#define LDST 40             // LDS row stride (bf16 elems): 80 B rows, 16B-aligned, bank shift 20/row

typedef float float4_t __attribute__((ext_vector_type(4)));
typedef __bf16 bf16x8_t __attribute__((ext_vector_type(8)));
typedef unsigned short ushort4_t __attribute__((ext_vector_type(4)));
typedef unsigned short ushort8_t __attribute__((ext_vector_type(8)));

// fp32 -> bf16 round-to-nearest-even
__device__ __forceinline__ unsigned short f2bf(float f) {
    unsigned int u = __float_as_uint(f);
    u += 0x7FFFu + ((u >> 16) & 1u);
    return (unsigned short)(u >> 16);
}

// Z = T2 (128 x 512, k=j) x W^T (rows j-contiguous); out[b,l] = sum_i Z[l,i]*t1[b,l,i]
// Block = (batch b, 64-wide i-tile). Registers budgeted to avoid spills at 128-reg cap.
__global__ __launch_bounds__(256, 4) void pdot_kernel(
    const float* __restrict__ t1, const float* __restrict__ t2,
    const int* __restrict__ pidx, const float* __restrict__ wgt,
    float* __restrict__ out)
{
    __shared__ unsigned short sA[2][NL * LDST];   // T2 tile bf16 [128 l][32 j + pad], double-buffered
    __shared__ unsigned short sB[2][BI * LDST];   // W  tile bf16 [64 i][32 j + pad]

    const int g  = blockIdx.x;
    const int b  = g & (NB - 1);   // batch in low bits: all 8 i-tiles of b share g%8 -> same XCD -> t1/t2 L2 reuse
    const int it = g >> 8;
    const int i0 = it * BI;

    const int t  = threadIdx.x;
    const int wv = t >> 6;
    const int ln = t & 63;
    const int nh = ln & 15;
    const int qd = ln >> 4;

    const int e = pidx[b];
    const float* aPtr = t2  + (size_t)b * (NL * ND2);
    const float* bPtr = wgt + (size_t)e * (ND1 * ND2) + (size_t)i0 * ND2;
    const float* t1p  = t1  + (size_t)b * (NL * ND1) + i0;

    float4_t acc[2][4];
    #pragma unroll
    for (int i = 0; i < 2; ++i)
        #pragma unroll
        for (int j = 0; j < 4; ++j) {
            float4_t z = {0.f, 0.f, 0.f, 0.f};
            acc[i][j] = z;
        }

    // staging map: thread owns rows rq+q*32, 16B chunk cq. A: q=0..3 (128 rows), B: q=0..1 (64 rows)
    const int rq = t >> 3;         // 0..31
    const int cq = (t & 7) * 4;    // fp32 col within tile

    const float* aRow = aPtr + (size_t)rq * ND2 + cq;
    const float* bRow = bPtr + (size_t)rq * ND2 + cq;

    float4_t ra[4], rb[2];         // prefetch registers: 24 VGPRs

    const int kf = qd * 8;         // fragment k-offset within tile

    // ---- prologue: load tile 0, store it, load tile 1
    #pragma unroll
    for (int q = 0; q < 4; ++q) ra[q] = *(const float4_t*)(aRow + (size_t)q * 32 * ND2);
    #pragma unroll
    for (int q = 0; q < 2; ++q) rb[q] = *(const float4_t*)(bRow + (size_t)q * 32 * ND2);

    #pragma unroll
    for (int q = 0; q < 4; ++q) {
        ushort4_t ua;
        ua.x = f2bf(ra[q].x); ua.y = f2bf(ra[q].y); ua.z = f2bf(ra[q].z); ua.w = f2bf(ra[q].w);
        *(ushort4_t*)(&sA[0][(rq + q * 32) * LDST + cq]) = ua;
    }
    #pragma unroll
    for (int q = 0; q < 2; ++q) {
        ushort4_t ub;
        ub.x = f2bf(rb[q].x); ub.y = f2bf(rb[q].y); ub.z = f2bf(rb[q].z); ub.w = f2bf(rb[q].w);
        *(ushort4_t*)(&sB[0][(rq + q * 32) * LDST + cq]) = ub;
    }
    #pragma unroll
    for (int q = 0; q < 4; ++q) ra[q] = *(const float4_t*)(aRow + (size_t)q * 32 * ND2 + BK);
    #pragma unroll
    for (int q = 0; q < 2; ++q) rb[q] = *(const float4_t*)(bRow + (size_t)q * 32 * ND2 + BK);
    __syncthreads();

    // ---- main loop: 1 barrier per k-tile; prefetch regs hide global latency under MFMA
    for (int i = 0; i < NKT; ++i) {
        const int cur = i & 1;

        bf16x8_t af[2];
        bf16x8_t bfr[4];
        #pragma unroll
        for (int ms = 0; ms < 2; ++ms) {
            const int row = wv * 32 + ms * 16 + nh;
            af[ms] = __builtin_bit_cast(bf16x8_t, *(ushort8_t*)(&sA[cur][row * LDST + kf]));
        }
        #pragma unroll
        for (int ns = 0; ns < 4; ++ns) {
            const int nr = ns * 16 + nh;
            bfr[ns] = __builtin_bit_cast(bf16x8_t, *(ushort8_t*)(&sB[cur][nr * LDST + kf]));
        }
        #pragma unroll
        for (int ms = 0; ms < 2; ++ms)
            #pragma unroll
            for (int ns = 0; ns < 4; ++ns)
                acc[ms][ns] = __builtin_amdgcn_mfma_f32_16x16x32_bf16(af[ms], bfr[ns], acc[ms][ns], 0, 0, 0);

        // stage tile i+1 into other buffer; refill prefetch regs with tile i+2
        if (i < NKT - 1) {
            const int nxt = cur ^ 1;
            #pragma unroll
            for (int q = 0; q < 4; ++q) {
                ushort4_t ua;
                ua.x = f2bf(ra[q].x); ua.y = f2bf(ra[q].y); ua.z = f2bf(ra[q].z); ua.w = f2bf(ra[q].w);
                *(ushort4_t*)(&sA[nxt][(rq + q * 32) * LDST + cq]) = ua;
            }
            #pragma unroll
            for (int q = 0; q < 2; ++q) {
                ushort4_t ub;
                ub.x = f2bf(rb[q].x); ub.y = f2bf(rb[q].y); ub.z = f2bf(rb[q].z); ub.w = f2bf(rb[q].w);
                *(ushort4_t*)(&sB[nxt][(rq + q * 32) * LDST + cq]) = ub;
            }
            if (i < NKT - 2) {
                const size_t ko = (size_t)(i + 2) * BK;
                #pragma unroll
                for (int q = 0; q < 4; ++q) ra[q] = *(const float4_t*)(aRow + (size_t)q * 32 * ND2 + ko);
                #pragma unroll
                for (int q = 0; q < 2; ++q) rb[q] = *(const float4_t*)(bRow + (size_t)q * 32 * ND2 + ko);
            }
        }
        __syncthreads();
    }

    // ---- epilogue: out[b,l] += sum over this i-tile of Z[l,i]*t1[l,i]
    // C/D: col(n=i) = ns*16+nh, row(m=l) = wv*32+ms*16+qd*4+r
    #pragma unroll
    for (int ms = 0; ms < 2; ++ms) {
        #pragma unroll
        for (int r = 0; r < 4; ++r) {
            const int row = wv * 32 + ms * 16 + qd * 4 + r;
            float ps = 0.f;
            #pragma unroll
            for (int ns = 0; ns < 4; ++ns) {
                const float tv = t1p[(size_t)row * ND1 + ns * 16 + nh];
                ps += acc[ms][ns][r] * tv;
            }
            ps += __shfl_xor(ps, 1);
            ps += __shfl_xor(ps, 2);
            ps += __shfl_xor(ps, 4);
            ps += __shfl_xor(ps, 8);
            if (nh == 0) atomicAdd(&out[b * NL + row], ps);
        }
    }
}

extern "C" void kernel_launch(void* const* d_in, const int* in_sizes, int n_in,
                              void* d_out, int out_size, void* d_ws, size_t ws_size,
                              hipStream_t stream)
{
    const float* t1  = (const float*)d_in[0];
    const float* t2  = (const float*)d_in[1];
    const int* pidx  = (const int*)d_in[2];
    const float* wgt = (const float*)d_in[3];
    float* out = (float*)d_out;

    hipMemsetAsync(out, 0, (size_t)out_size * sizeof(float), stream);
    pdot_kernel<<<dim3(NB * (ND1 / BI)), dim3(256), 0, stream>>>(t1, t2, pidx, wgt, out);
}